// Round 1
// baseline (11109.107 us; speedup 1.0000x reference)
//
#include <hip/hip_runtime.h>

#define B_ 256
#define T_ 128
#define M_ (B_ * T_)

__device__ __forceinline__ float sigf(float x) { return 1.0f / (1.0f + __expf(-x)); }
__device__ __forceinline__ float dot4(float4 a, float4 b) {
  return a.x * b.x + a.y * b.y + a.z * b.z + a.w * b.w;
}

// ---------------------------------------------------------------------------
// prep: combined dialogue weight matrix [1024][512] = [w_ih_d(250)|pad(6)|w_hh_d(256)]
// plus combined biases (b_ih + b_hh) for every LSTM cell.
// ---------------------------------------------------------------------------
__global__ void prep_kernel(const float* __restrict__ w_ih_d, const float* __restrict__ w_hh_d,
                            const float* __restrict__ b_ih_d, const float* __restrict__ b_hh_d,
                            const float* __restrict__ b_ih0, const float* __restrict__ b_hh0,
                            const float* __restrict__ b_ih1, const float* __restrict__ b_hh1,
                            const float* __restrict__ b_ih2, const float* __restrict__ b_hh2,
                            float* __restrict__ wcomb, float* __restrict__ biasd,
                            float* __restrict__ bias0, float* __restrict__ bias1,
                            float* __restrict__ bias2) {
  int idx = blockIdx.x * blockDim.x + threadIdx.x;
  int stride = gridDim.x * blockDim.x;
  for (int i = idx; i < 1024 * 512; i += stride) {
    int j = i >> 9, k = i & 511;
    float v;
    if (k < 250) v = w_ih_d[j * 250 + k];
    else if (k < 256) v = 0.0f;
    else v = w_hh_d[j * 256 + (k - 256)];
    wcomb[i] = v;
  }
  for (int i = idx; i < 1024; i += stride) biasd[i] = b_ih_d[i] + b_hh_d[i];
  for (int i = idx; i < 512; i += stride) bias0[i] = b_ih0[i] + b_hh0[i];
  for (int i = idx; i < 256; i += stride) bias1[i] = b_ih1[i] + b_hh1[i];
  for (int i = idx; i < 512; i += stride) bias2[i] = b_ih2[i] + b_hh2[i];
}

// ---------------------------------------------------------------------------
// proj_gemm: gx[t*B+b][n] = umask[b][t] * sum_k mod[b][t][k]*W[n][k]  + bias[n]
// Tiled fp32 GEMM, 64x64x16, 256 threads, 4x4 per thread. M = T*B = 32768.
// Rows m = t*B+b; each 64-row tile shares one t (m0 % 256 + 63 <= 255).
// ---------------------------------------------------------------------------
#define BK 16
__global__ __launch_bounds__(256) void proj_gemm(
    const float* __restrict__ X, const float* __restrict__ W,
    const float* __restrict__ bias, const float* __restrict__ umask,
    float* __restrict__ C, int K, int N) {
  __shared__ __align__(16) float As[BK][68];   // [k][m], pad 68 keeps float4 align + low conflicts
  __shared__ __align__(16) float Ws[BK][68];   // [k][n]
  const int tid = threadIdx.x;
  const int n0 = blockIdx.x * 64;
  const int m0 = blockIdx.y * 64;
  const int t = m0 >> 8;
  const int b0 = m0 & (B_ - 1);
  const int lrow = tid >> 2, kq = tid & 3;
  const int tx = tid & 15, ty = tid >> 4;
  const float* Arow = X + ((size_t)(b0 + lrow) * T_ + t) * K;
  const float* Wrow = W + (size_t)(n0 + lrow) * K;
  float acc[4][4] = {};
  for (int k0 = 0; k0 < K; k0 += BK) {
    if (k0 + BK <= K) {  // uniform branch per tile
      float4 av = *reinterpret_cast<const float4*>(Arow + k0 + kq * 4);
      float4 wv = *reinterpret_cast<const float4*>(Wrow + k0 + kq * 4);
      As[kq * 4 + 0][lrow] = av.x; As[kq * 4 + 1][lrow] = av.y;
      As[kq * 4 + 2][lrow] = av.z; As[kq * 4 + 3][lrow] = av.w;
      Ws[kq * 4 + 0][lrow] = wv.x; Ws[kq * 4 + 1][lrow] = wv.y;
      Ws[kq * 4 + 2][lrow] = wv.z; Ws[kq * 4 + 3][lrow] = wv.w;
    } else {
#pragma unroll
      for (int e = 0; e < 4; e++) {
        int k = k0 + kq * 4 + e;
        As[kq * 4 + e][lrow] = (k < K) ? Arow[k] : 0.0f;
        Ws[kq * 4 + e][lrow] = (k < K) ? Wrow[k] : 0.0f;
      }
    }
    __syncthreads();
#pragma unroll
    for (int kk = 0; kk < BK; kk++) {
      float4 a4 = *reinterpret_cast<const float4*>(&As[kk][ty * 4]);
      float4 w4 = *reinterpret_cast<const float4*>(&Ws[kk][tx * 4]);
      float a[4] = {a4.x, a4.y, a4.z, a4.w};
      float w[4] = {w4.x, w4.y, w4.z, w4.w};
#pragma unroll
      for (int i = 0; i < 4; i++)
#pragma unroll
        for (int j = 0; j < 4; j++) acc[i][j] += a[i] * w[j];
    }
    __syncthreads();
  }
  float4 bv = *reinterpret_cast<const float4*>(bias + n0 + tx * 4);
#pragma unroll
  for (int i = 0; i < 4; i++) {
    int m = m0 + ty * 4 + i;
    int b = b0 + ty * 4 + i;
    float um = umask[b * T_ + t];
    float4 o;
    o.x = acc[i][0] * um + bv.x; o.y = acc[i][1] * um + bv.y;
    o.z = acc[i][2] * um + bv.z; o.w = acc[i][3] * um + bv.w;
    *reinterpret_cast<float4*>(C + (size_t)m * N + n0 + tx * 4) = o;
  }
}

// ---------------------------------------------------------------------------
// mod_lstm: per-modality LSTM scan. Batch rows are independent -> each block
// owns 4 rows, loops all T steps with only __syncthreads(). h in LDS, c in
// registers, gate matvec reuses one w_hh row across the 4 rows.
// Also fuses the per-step FC + tanh + umask, writing straight into dfeat.
// ---------------------------------------------------------------------------
template <int H, int F, int COLOFF>
__device__ __forceinline__ void mod_body(
    const float* __restrict__ gx, const float* __restrict__ whh,
    const float* __restrict__ fcw, const float* __restrict__ fcb,
    const float* __restrict__ umask, float* __restrict__ dfeat,
    int b0, int tid, float (*hs)[128], float (*gbuf)[512]) {
  constexpr int H4 = 4 * H;
  constexpr int NG = H4 / 256;        // gates per thread (2 or 1)
  constexpr int NU = (4 * H) / 256;   // cell units per thread (2 or 1)
  float creg[NU];
#pragma unroll
  for (int q = 0; q < NU; q++) creg[q] = 0.f;
  for (int u = tid; u < 4 * H; u += 256) hs[u / H][u % H] = 0.f;
  __syncthreads();
  for (int t = 0; t < T_; t++) {
    // gates: acc[g][r] = sum_k h[r][k] * w_hh[jj_g][k]
    float acc[NG][4];
#pragma unroll
    for (int g = 0; g < NG; g++)
#pragma unroll
      for (int r = 0; r < 4; r++) acc[g][r] = 0.f;
#pragma unroll 4
    for (int k = 0; k < H; k += 4) {
      float4 h4[4];
#pragma unroll
      for (int r = 0; r < 4; r++) h4[r] = *reinterpret_cast<const float4*>(&hs[r][k]);
#pragma unroll
      for (int g = 0; g < NG; g++) {
        const int jj = tid + (g << 8);
        float4 w4 = *reinterpret_cast<const float4*>(&whh[(size_t)jj * H + k]);
#pragma unroll
        for (int r = 0; r < 4; r++) acc[g][r] += dot4(w4, h4[r]);
      }
    }
#pragma unroll
    for (int g = 0; g < NG; g++) {
      const int jj = tid + (g << 8);
#pragma unroll
      for (int r = 0; r < 4; r++)
        gbuf[r][jj] = acc[g][r] + gx[((size_t)t * B_ + b0 + r) * H4 + jj];
    }
    __syncthreads();
    // cell (torch gate order i,f,g,o) + extra tanh on h
#pragma unroll
    for (int q = 0; q < NU; q++) {
      const int u = tid + (q << 8);
      const int r = u / H, j = u % H;
      float i_ = sigf(gbuf[r][j]);
      float f_ = sigf(gbuf[r][H + j]);
      float g_ = tanhf(gbuf[r][2 * H + j]);
      float o_ = sigf(gbuf[r][3 * H + j]);
      float c2 = f_ * creg[q] + i_ * g_;
      creg[q] = c2;
      hs[r][j] = tanhf(o_ * tanhf(c2));   // extra tanh on hidden state
    }
    __syncthreads();
    // FC -> tanh -> *umask -> dfeat
    if (tid < F) {
      const float* fw = fcw + (size_t)tid * H;
      float fb = fcb[tid];
      float a[4];
#pragma unroll
      for (int r = 0; r < 4; r++) a[r] = fb;
#pragma unroll 4
      for (int k = 0; k < H; k += 4) {
        float4 w4 = *reinterpret_cast<const float4*>(&fw[k]);
#pragma unroll
        for (int r = 0; r < 4; r++)
          a[r] += dot4(w4, *reinterpret_cast<const float4*>(&hs[r][k]));
      }
#pragma unroll
      for (int r = 0; r < 4; r++) {
        float um = umask[(b0 + r) * T_ + t];
        dfeat[((size_t)t * B_ + b0 + r) * 250 + COLOFF + tid] = tanhf(a[r]) * um;
      }
    }
    // no sync needed here: next-step gate phase only reads hs; gbuf writers
    // are ordered by the sync after the gate phase.
  }
}

struct ModParams {
  const float* gx0; const float* gx1; const float* gx2;
  const float* whh0; const float* whh1; const float* whh2;
  const float* fcw0; const float* fcw1; const float* fcw2;
  const float* fcb0; const float* fcb1; const float* fcb2;
};

__global__ __launch_bounds__(256) void mod_lstm(ModParams p,
    const float* __restrict__ umask, float* __restrict__ dfeat) {
  __shared__ __align__(16) float hs[4][128];
  __shared__ __align__(16) float gbuf[4][512];
  const int mi = blockIdx.x >> 6;
  const int b0 = (blockIdx.x & 63) * 4;
  const int tid = threadIdx.x;
  if (mi == 0)      mod_body<128, 100,   0>(p.gx0, p.whh0, p.fcw0, p.fcb0, umask, dfeat, b0, tid, hs, gbuf);
  else if (mi == 1) mod_body< 64,  50, 100>(p.gx1, p.whh1, p.fcw1, p.fcb1, umask, dfeat, b0, tid, hs, gbuf);
  else              mod_body<128, 100, 150>(p.gx2, p.whh2, p.fcw2, p.fcb2, umask, dfeat, b0, tid, hs, gbuf);
}

// ---------------------------------------------------------------------------
// dlg_lstm: dialogue LSTM scan + fc_out + smax + log_softmax, fused.
// 64 blocks x 512 threads, 4 batch rows per block; thread owns 2 gate rows of
// wcomb and accumulates them for all 4 rows (register reuse of weights).
// ---------------------------------------------------------------------------
__global__ __launch_bounds__(512) void dlg_lstm(
    const float* __restrict__ dfeat, const float* __restrict__ wcomb,
    const float* __restrict__ biasd, const float* __restrict__ fcow,
    const float* __restrict__ fcob, const float* __restrict__ smw,
    const float* __restrict__ smb, float* __restrict__ out) {
  const int tid = threadIdx.x;
  const int b0 = blockIdx.x * 4;
  __shared__ __align__(16) float xf[4][256];     // dfeat tile (250 + zero pad)
  __shared__ __align__(16) float hs[4][256];
  __shared__ __align__(16) float gbuf[4][1024];
  __shared__ __align__(16) float fco[4][128];
  __shared__ float lbuf[4][6];
  for (int u = tid; u < 4 * 256; u += 512) {
    xf[u >> 8][u & 255] = 0.f;
    hs[u >> 8][u & 255] = 0.f;
  }
  float creg[2] = {0.f, 0.f};
  const float bs0 = biasd[tid], bs1 = biasd[tid + 512];
  const float* __restrict__ w0 = wcomb + (size_t)tid * 512;
  const float* __restrict__ w1 = wcomb + (size_t)(tid + 512) * 512;
  __syncthreads();
  for (int t = 0; t < T_; t++) {
    // stage dfeat rows
#pragma unroll
    for (int r = 0; r < 4; r++)
      if (tid < 250) xf[r][tid] = dfeat[((size_t)t * B_ + b0 + r) * 250 + tid];
    __syncthreads();
    // gates: 2 gate rows per thread, 4 batch rows each
    float a0[4], a1[4];
#pragma unroll
    for (int r = 0; r < 4; r++) { a0[r] = bs0; a1[r] = bs1; }
#pragma unroll 2
    for (int k = 0; k < 256; k += 4) {         // input-projection part (k<250 real)
      float4 x4[4];
#pragma unroll
      for (int r = 0; r < 4; r++) x4[r] = *reinterpret_cast<const float4*>(&xf[r][k]);
      float4 wa = *reinterpret_cast<const float4*>(&w0[k]);
      float4 wb = *reinterpret_cast<const float4*>(&w1[k]);
#pragma unroll
      for (int r = 0; r < 4; r++) { a0[r] += dot4(wa, x4[r]); a1[r] += dot4(wb, x4[r]); }
    }
#pragma unroll 2
    for (int k = 0; k < 256; k += 4) {         // recurrent part
      float4 h4[4];
#pragma unroll
      for (int r = 0; r < 4; r++) h4[r] = *reinterpret_cast<const float4*>(&hs[r][k]);
      float4 wa = *reinterpret_cast<const float4*>(&w0[256 + k]);
      float4 wb = *reinterpret_cast<const float4*>(&w1[256 + k]);
#pragma unroll
      for (int r = 0; r < 4; r++) { a0[r] += dot4(wa, h4[r]); a1[r] += dot4(wb, h4[r]); }
    }
#pragma unroll
    for (int r = 0; r < 4; r++) { gbuf[r][tid] = a0[r]; gbuf[r][tid + 512] = a1[r]; }
    __syncthreads();
    // cell (no extra tanh for dialogue LSTM)
#pragma unroll
    for (int q = 0; q < 2; q++) {
      const int u = tid + (q << 9);
      const int r = u >> 8, j = u & 255;
      float i_ = sigf(gbuf[r][j]);
      float f_ = sigf(gbuf[r][256 + j]);
      float g_ = tanhf(gbuf[r][512 + j]);
      float o_ = sigf(gbuf[r][768 + j]);
      float c2 = f_ * creg[q] + i_ * g_;
      creg[q] = c2;
      hs[r][j] = o_ * tanhf(c2);
    }
    __syncthreads();
    // fc_out + tanh
    {
      const int r = tid >> 7, f = tid & 127;
      const float* fw = fcow + (size_t)f * 256;
      float a = fcob[f];
#pragma unroll 4
      for (int k = 0; k < 256; k += 4)
        a += dot4(*reinterpret_cast<const float4*>(&fw[k]),
                  *reinterpret_cast<const float4*>(&hs[r][k]));
      fco[r][f] = tanhf(a);
    }
    __syncthreads();
    // logits
    if (tid < 24) {
      const int r = tid / 6, c = tid % 6;
      float a = smb[c];
      const float* sw = smw + c * 128;
      for (int k = 0; k < 128; k++) a += sw[k] * fco[r][k];
      lbuf[r][c] = a;
    }
    __syncthreads();
    // log_softmax over classes, write [B][T][6]
    if (tid < 4) {
      const int r = tid;
      float mx = lbuf[r][0];
#pragma unroll
      for (int c = 1; c < 6; c++) mx = fmaxf(mx, lbuf[r][c]);
      float s = 0.f;
#pragma unroll
      for (int c = 0; c < 6; c++) s += __expf(lbuf[r][c] - mx);
      float lse = mx + logf(s);
#pragma unroll
      for (int c = 0; c < 6; c++)
        out[((size_t)(b0 + r) * T_ + t) * 6 + c] = lbuf[r][c] - lse;
    }
    // next-iteration xf store + the sync after it order lbuf/fco reuse
  }
}

// ---------------------------------------------------------------------------
extern "C" void kernel_launch(void* const* d_in, const int* in_sizes, int n_in,
                              void* d_out, int out_size, void* d_ws, size_t ws_size,
                              hipStream_t stream) {
  const float* mod0  = (const float*)d_in[0];
  const float* mod1  = (const float*)d_in[1];
  const float* mod2  = (const float*)d_in[2];
  const float* umask = (const float*)d_in[3];
  const float* w_ih0 = (const float*)d_in[4];
  const float* w_hh0 = (const float*)d_in[5];
  const float* b_ih0 = (const float*)d_in[6];
  const float* b_hh0 = (const float*)d_in[7];
  const float* fc_w0 = (const float*)d_in[8];
  const float* fc_b0 = (const float*)d_in[9];
  const float* w_ih1 = (const float*)d_in[10];
  const float* w_hh1 = (const float*)d_in[11];
  const float* b_ih1 = (const float*)d_in[12];
  const float* b_hh1 = (const float*)d_in[13];
  const float* fc_w1 = (const float*)d_in[14];
  const float* fc_b1 = (const float*)d_in[15];
  const float* w_ih2 = (const float*)d_in[16];
  const float* w_hh2 = (const float*)d_in[17];
  const float* b_ih2 = (const float*)d_in[18];
  const float* b_hh2 = (const float*)d_in[19];
  const float* fc_w2 = (const float*)d_in[20];
  const float* fc_b2 = (const float*)d_in[21];
  const float* w_ih_d = (const float*)d_in[22];
  const float* w_hh_d = (const float*)d_in[23];
  const float* b_ih_d = (const float*)d_in[24];
  const float* b_hh_d = (const float*)d_in[25];
  const float* fco_w  = (const float*)d_in[26];
  const float* fco_b  = (const float*)d_in[27];
  const float* sm_w   = (const float*)d_in[28];
  const float* sm_b   = (const float*)d_in[29];

  // workspace layout (floats); total ~193 MiB
  float* ws    = (float*)d_ws;
  float* gx0   = ws;                                  // 32768*512
  float* gx1   = gx0   + (size_t)M_ * 512;            // 32768*256
  float* gx2   = gx1   + (size_t)M_ * 256;            // 32768*512
  float* dfeat = gx2   + (size_t)M_ * 512;            // 32768*250
  float* wcomb = dfeat + (size_t)M_ * 250;            // 1024*512
  float* biasd = wcomb + 1024 * 512;                  // 1024
  float* bias0 = biasd + 1024;                        // 512
  float* bias1 = bias0 + 512;                         // 256
  float* bias2 = bias1 + 256;                         // 512

  prep_kernel<<<256, 256, 0, stream>>>(w_ih_d, w_hh_d, b_ih_d, b_hh_d,
      b_ih0, b_hh0, b_ih1, b_hh1, b_ih2, b_hh2, wcomb, biasd, bias0, bias1, bias2);

  proj_gemm<<<dim3(8, M_ / 64), 256, 0, stream>>>(mod0, w_ih0, bias0, umask, gx0, 300, 512);
  proj_gemm<<<dim3(4, M_ / 64), 256, 0, stream>>>(mod1, w_ih1, bias1, umask, gx1, 100, 256);
  proj_gemm<<<dim3(8, M_ / 64), 256, 0, stream>>>(mod2, w_ih2, bias2, umask, gx2, 512, 512);

  ModParams p;
  p.gx0 = gx0; p.gx1 = gx1; p.gx2 = gx2;
  p.whh0 = w_hh0; p.whh1 = w_hh1; p.whh2 = w_hh2;
  p.fcw0 = fc_w0; p.fcw1 = fc_w1; p.fcw2 = fc_w2;
  p.fcb0 = fc_b0; p.fcb1 = fc_b1; p.fcb2 = fc_b2;
  mod_lstm<<<192, 256, 0, stream>>>(p, umask, dfeat);

  dlg_lstm<<<64, 512, 0, stream>>>(dfeat, wcomb, biasd, fco_w, fco_b, sm_w, sm_b,
                                   (float*)d_out);
}

// Round 2
// 7242.265 us; speedup vs baseline: 1.5339x; 1.5339x over previous
//
#include <hip/hip_runtime.h>

#define B_ 256
#define T_ 128
#define M_ (B_ * T_)
#define DH_ 256

__device__ __forceinline__ float sigf(float x) { return 1.0f / (1.0f + __expf(-x)); }
__device__ __forceinline__ float dot4(float4 a, float4 b) {
  return a.x * b.x + a.y * b.y + a.z * b.z + a.w * b.w;
}

// ---------------------------------------------------------------------------
// prep: combined biases, padded w_ih_d ([1024][256], cols 250..255 = 0),
// zero dfeat pad columns, zero the group-barrier state.
// ---------------------------------------------------------------------------
__global__ void prep_kernel(const float* __restrict__ w_ih_d,
                            const float* __restrict__ b_ih_d, const float* __restrict__ b_hh_d,
                            const float* __restrict__ b_ih0, const float* __restrict__ b_hh0,
                            const float* __restrict__ b_ih1, const float* __restrict__ b_hh1,
                            const float* __restrict__ b_ih2, const float* __restrict__ b_hh2,
                            float* __restrict__ wihd, float* __restrict__ dfeat,
                            float* __restrict__ biasd, float* __restrict__ bias0,
                            float* __restrict__ bias1, float* __restrict__ bias2,
                            int* __restrict__ bar) {
  int idx = blockIdx.x * blockDim.x + threadIdx.x;
  int stride = gridDim.x * blockDim.x;
  for (int i = idx; i < 1024 * 256; i += stride) {
    int j = i >> 8, k = i & 255;
    wihd[i] = (k < 250) ? w_ih_d[j * 250 + k] : 0.0f;
  }
  for (int i = idx; i < M_ * 6; i += stride)         // zero dfeat pad cols 250..255
    dfeat[(size_t)(i / 6) * 256 + 250 + (i % 6)] = 0.0f;
  for (int i = idx; i < 1024; i += stride) biasd[i] = b_ih_d[i] + b_hh_d[i];
  for (int i = idx; i < 512; i += stride) bias0[i] = b_ih0[i] + b_hh0[i];
  for (int i = idx; i < 256; i += stride) bias1[i] = b_ih1[i] + b_hh1[i];
  for (int i = idx; i < 512; i += stride) bias2[i] = b_ih2[i] + b_hh2[i];
  for (int i = idx; i < 512; i += stride) bar[i] = 0;
}

// ---------------------------------------------------------------------------
// proj_gemm: C[m][n] = (BTX ? umask : 1) * sum_k A[m][k]*W[n][k] + bias[n]
// BTX: A is [B][T][K] with m = t*B+b; else A is [M][K] row-major.
// Tiled fp32 GEMM, 64x64x16, 256 threads, 4x4 per thread.
// ---------------------------------------------------------------------------
#define BK 16
template <bool BTX>
__global__ __launch_bounds__(256) void proj_gemm(
    const float* __restrict__ X, const float* __restrict__ W,
    const float* __restrict__ bias, const float* __restrict__ umask,
    float* __restrict__ C, int K, int N) {
  __shared__ __align__(16) float As[BK][68];
  __shared__ __align__(16) float Ws[BK][68];
  const int tid = threadIdx.x;
  const int n0 = blockIdx.x * 64;
  const int m0 = blockIdx.y * 64;
  const int t = m0 >> 8;
  const int b0 = m0 & (B_ - 1);
  const int lrow = tid >> 2, kq = tid & 3;
  const int tx = tid & 15, ty = tid >> 4;
  const float* Arow;
  if constexpr (BTX) Arow = X + ((size_t)(b0 + lrow) * T_ + t) * K;
  else               Arow = X + (size_t)(m0 + lrow) * K;
  const float* Wrow = W + (size_t)(n0 + lrow) * K;
  float acc[4][4] = {};
  for (int k0 = 0; k0 < K; k0 += BK) {
    if (k0 + BK <= K) {
      float4 av = *reinterpret_cast<const float4*>(Arow + k0 + kq * 4);
      float4 wv = *reinterpret_cast<const float4*>(Wrow + k0 + kq * 4);
      As[kq * 4 + 0][lrow] = av.x; As[kq * 4 + 1][lrow] = av.y;
      As[kq * 4 + 2][lrow] = av.z; As[kq * 4 + 3][lrow] = av.w;
      Ws[kq * 4 + 0][lrow] = wv.x; Ws[kq * 4 + 1][lrow] = wv.y;
      Ws[kq * 4 + 2][lrow] = wv.z; Ws[kq * 4 + 3][lrow] = wv.w;
    } else {
#pragma unroll
      for (int e = 0; e < 4; e++) {
        int k = k0 + kq * 4 + e;
        As[kq * 4 + e][lrow] = (k < K) ? Arow[k] : 0.0f;
        Ws[kq * 4 + e][lrow] = (k < K) ? Wrow[k] : 0.0f;
      }
    }
    __syncthreads();
#pragma unroll
    for (int kk = 0; kk < BK; kk++) {
      float4 a4 = *reinterpret_cast<const float4*>(&As[kk][ty * 4]);
      float4 w4 = *reinterpret_cast<const float4*>(&Ws[kk][tx * 4]);
      float a[4] = {a4.x, a4.y, a4.z, a4.w};
      float w[4] = {w4.x, w4.y, w4.z, w4.w};
#pragma unroll
      for (int i = 0; i < 4; i++)
#pragma unroll
        for (int j = 0; j < 4; j++) acc[i][j] += a[i] * w[j];
    }
    __syncthreads();
  }
  float4 bv = *reinterpret_cast<const float4*>(bias + n0 + tx * 4);
#pragma unroll
  for (int i = 0; i < 4; i++) {
    int m = m0 + ty * 4 + i;
    float um = 1.0f;
    if constexpr (BTX) um = umask[(b0 + ty * 4 + i) * T_ + t];
    float4 o;
    o.x = acc[i][0] * um + bv.x; o.y = acc[i][1] * um + bv.y;
    o.z = acc[i][2] * um + bv.z; o.w = acc[i][3] * um + bv.w;
    *reinterpret_cast<float4*>(C + (size_t)m * N + n0 + tx * 4) = o;
  }
}

// ---------------------------------------------------------------------------
// mod_lstm: per-modality LSTM scan (unchanged structure, dfeat stride 256).
// ---------------------------------------------------------------------------
template <int H, int F, int COLOFF>
__device__ __forceinline__ void mod_body(
    const float* __restrict__ gx, const float* __restrict__ whh,
    const float* __restrict__ fcw, const float* __restrict__ fcb,
    const float* __restrict__ umask, float* __restrict__ dfeat,
    int b0, int tid, float (*hs)[128], float (*gbuf)[512]) {
  constexpr int H4 = 4 * H;
  constexpr int NG = H4 / 256;
  constexpr int NU = (4 * H) / 256;
  float creg[NU];
#pragma unroll
  for (int q = 0; q < NU; q++) creg[q] = 0.f;
  for (int u = tid; u < 4 * H; u += 256) hs[u / H][u % H] = 0.f;
  __syncthreads();
  for (int t = 0; t < T_; t++) {
    float acc[NG][4];
#pragma unroll
    for (int g = 0; g < NG; g++)
#pragma unroll
      for (int r = 0; r < 4; r++) acc[g][r] = 0.f;
#pragma unroll 4
    for (int k = 0; k < H; k += 4) {
      float4 h4[4];
#pragma unroll
      for (int r = 0; r < 4; r++) h4[r] = *reinterpret_cast<const float4*>(&hs[r][k]);
#pragma unroll
      for (int g = 0; g < NG; g++) {
        const int jj = tid + (g << 8);
        float4 w4 = *reinterpret_cast<const float4*>(&whh[(size_t)jj * H + k]);
#pragma unroll
        for (int r = 0; r < 4; r++) acc[g][r] += dot4(w4, h4[r]);
      }
    }
#pragma unroll
    for (int g = 0; g < NG; g++) {
      const int jj = tid + (g << 8);
#pragma unroll
      for (int r = 0; r < 4; r++)
        gbuf[r][jj] = acc[g][r] + gx[((size_t)t * B_ + b0 + r) * H4 + jj];
    }
    __syncthreads();
#pragma unroll
    for (int q = 0; q < NU; q++) {
      const int u = tid + (q << 8);
      const int r = u / H, j = u % H;
      float i_ = sigf(gbuf[r][j]);
      float f_ = sigf(gbuf[r][H + j]);
      float g_ = tanhf(gbuf[r][2 * H + j]);
      float o_ = sigf(gbuf[r][3 * H + j]);
      float c2 = f_ * creg[q] + i_ * g_;
      creg[q] = c2;
      hs[r][j] = tanhf(o_ * tanhf(c2));
    }
    __syncthreads();
    if (tid < F) {
      const float* fw = fcw + (size_t)tid * H;
      float fb = fcb[tid];
      float a[4];
#pragma unroll
      for (int r = 0; r < 4; r++) a[r] = fb;
#pragma unroll 4
      for (int k = 0; k < H; k += 4) {
        float4 w4 = *reinterpret_cast<const float4*>(&fw[k]);
#pragma unroll
        for (int r = 0; r < 4; r++)
          a[r] += dot4(w4, *reinterpret_cast<const float4*>(&hs[r][k]));
      }
#pragma unroll
      for (int r = 0; r < 4; r++) {
        float um = umask[(b0 + r) * T_ + t];
        dfeat[((size_t)t * B_ + b0 + r) * 256 + COLOFF + tid] = tanhf(a[r]) * um;
      }
    }
  }
}

struct ModParams {
  const float* gx0; const float* gx1; const float* gx2;
  const float* whh0; const float* whh1; const float* whh2;
  const float* fcw0; const float* fcw1; const float* fcw2;
  const float* fcb0; const float* fcb1; const float* fcb2;
};

__global__ __launch_bounds__(256) void mod_lstm(ModParams p,
    const float* __restrict__ umask, float* __restrict__ dfeat) {
  __shared__ __align__(16) float hs[4][128];
  __shared__ __align__(16) float gbuf[4][512];
  const int mi = blockIdx.x >> 6;
  const int b0 = (blockIdx.x & 63) * 4;
  const int tid = threadIdx.x;
  if (mi == 0)      mod_body<128, 100,   0>(p.gx0, p.whh0, p.fcw0, p.fcb0, umask, dfeat, b0, tid, hs, gbuf);
  else if (mi == 1) mod_body< 64,  50, 100>(p.gx1, p.whh1, p.fcw1, p.fcb1, umask, dfeat, b0, tid, hs, gbuf);
  else              mod_body<128, 100, 150>(p.gx2, p.whh2, p.fcw2, p.fcb2, umask, dfeat, b0, tid, hs, gbuf);
}

// ---------------------------------------------------------------------------
// dlg_recur: dialogue LSTM recurrence with LDS-resident w_hh chunks.
// 256 blocks = 16 batch-groups (16 rows) x 16 unit-chunks (16 units = 64 gate
// rows). Weights loaded to LDS ONCE; per step: stage h[t-1] (group rows) from
// global, 64x16x256 LDS GEMM (8-way k-split + LDS reduction), cell update,
// write h[t] slice to hall[t], per-group device-scope barrier.
// ---------------------------------------------------------------------------
#define WTS 68
#define HTS 20
#define RDS 17
#define DLG_NF (256 * WTS + 256 * HTS + 8 * 64 * RDS)
#define DLG_LDS_BYTES (DLG_NF * 4)

__global__ __launch_bounds__(256) void dlg_recur(
    const float* __restrict__ gxd, const float* __restrict__ whh,
    float* __restrict__ hall, int* __restrict__ bar) {
  extern __shared__ float smem[];
  float* wT  = smem;               // [256][WTS]  wT[k][lr]
  float* hT  = smem + 256 * WTS;   // [256][HTS]  hT[k][br]
  float* red = hT + 256 * HTS;     // [8][64][RDS]
  const int tid = threadIdx.x;
  const int g = blockIdx.x >> 4;
  const int c = blockIdx.x & 15;
  int* cnt = bar + g * 32;         // 128B-separated per group
  int* gen = bar + g * 32 + 16;

  {  // load w_hh chunk transposed into LDS (once)
    const int lr = tid >> 2, kq = tid & 3;
    const int gate = lr >> 4, uu = lr & 15;
    const float* wrow = whh + (size_t)(gate * 256 + c * 16 + uu) * 256 + kq * 64;
#pragma unroll
    for (int i = 0; i < 64; i += 4) {
      float4 v = *reinterpret_cast<const float4*>(wrow + i);
      const int kb = kq * 64 + i;
      wT[(kb + 0) * WTS + lr] = v.x;
      wT[(kb + 1) * WTS + lr] = v.y;
      wT[(kb + 2) * WTS + lr] = v.z;
      wT[(kb + 3) * WTS + lr] = v.w;
    }
  }
  const int rt = tid & 15;            // row tile (4 gate rows)
  const int bt = (tid >> 4) & 1;      // batch tile (8 rows)
  const int ks = tid >> 5;            // k-slice (32 k each)
  const int uu_c = tid >> 4;          // cell phase: unit in chunk
  const int br_c = tid & 15;          // cell phase: batch row in group
  float creg = 0.f;

  for (int t = 0; t < T_; t++) {
    if (tid == 0 && t > 0) {
      while (__hip_atomic_load(gen, __ATOMIC_ACQUIRE, __HIP_MEMORY_SCOPE_AGENT) < t)
        __builtin_amdgcn_s_sleep(2);
    }
    __syncthreads();                       // S1: gen[g] >= t
    if (t == 0) {
      for (int e = tid; e < 256 * HTS; e += 256) hT[e] = 0.f;
    } else {
      const int br = tid & 15, kb = (tid >> 4) * 16;
      const float* src = hall + ((size_t)(t - 1) * B_ + g * 16 + br) * DH_ + kb;
#pragma unroll
      for (int q = 0; q < 4; q++) {
        float4 v = reinterpret_cast<const float4*>(src)[q];
        const int k = kb + q * 4;
        hT[(k + 0) * HTS + br] = v.x;
        hT[(k + 1) * HTS + br] = v.y;
        hT[(k + 2) * HTS + br] = v.z;
        hT[(k + 3) * HTS + br] = v.w;
      }
    }
    __syncthreads();                       // S2: hT staged

    float acc[4][8];
#pragma unroll
    for (int i = 0; i < 4; i++)
#pragma unroll
      for (int j = 0; j < 8; j++) acc[i][j] = 0.f;
#pragma unroll 4
    for (int kk = ks * 32; kk < ks * 32 + 32; kk++) {
      float4 wv = *reinterpret_cast<const float4*>(&wT[kk * WTS + rt * 4]);
      float4 ha = *reinterpret_cast<const float4*>(&hT[kk * HTS + bt * 8]);
      float4 hb = *reinterpret_cast<const float4*>(&hT[kk * HTS + bt * 8 + 4]);
      float w[4] = {wv.x, wv.y, wv.z, wv.w};
      float h[8] = {ha.x, ha.y, ha.z, ha.w, hb.x, hb.y, hb.z, hb.w};
#pragma unroll
      for (int i = 0; i < 4; i++)
#pragma unroll
        for (int j = 0; j < 8; j++) acc[i][j] += w[i] * h[j];
    }
#pragma unroll
    for (int i = 0; i < 4; i++)
#pragma unroll
      for (int j = 0; j < 8; j++)
        red[(ks * 64 + rt * 4 + i) * RDS + bt * 8 + j] = acc[i][j];
    __syncthreads();                       // S3: partials ready

    // cell: thread -> (unit uu_c, batch row br_c)
    float s[4];
    const float* gxr = gxd + ((size_t)t * B_ + g * 16 + br_c) * 1024 + c * 16 + uu_c;
#pragma unroll
    for (int gate = 0; gate < 4; gate++) {
      const int lr = gate * 16 + uu_c;
      float a = gxr[gate * 256];
#pragma unroll
      for (int k2 = 0; k2 < 8; k2++) a += red[(k2 * 64 + lr) * RDS + br_c];
      s[gate] = a;
    }
    float i_ = sigf(s[0]), f_ = sigf(s[1]), g_ = tanhf(s[2]), o_ = sigf(s[3]);
    float c2 = f_ * creg + i_ * g_;
    creg = c2;
    hall[((size_t)t * B_ + g * 16 + br_c) * DH_ + c * 16 + uu_c] = o_ * tanhf(c2);

    __threadfence();
    __syncthreads();                       // S4: all writes issued+fenced
    if (tid == 0) {
      int prev = __hip_atomic_fetch_add(cnt, 1, __ATOMIC_ACQ_REL, __HIP_MEMORY_SCOPE_AGENT);
      if (prev == 15) {
        __hip_atomic_store(cnt, 0, __ATOMIC_RELAXED, __HIP_MEMORY_SCOPE_AGENT);
        __hip_atomic_fetch_add(gen, 1, __ATOMIC_RELEASE, __HIP_MEMORY_SCOPE_AGENT);
      }
    }
  }
}

// ---------------------------------------------------------------------------
// out_head: fc_out + tanh + smax + log_softmax over all 32768 (t,b) rows.
// ---------------------------------------------------------------------------
__global__ __launch_bounds__(256) void out_head(
    const float* __restrict__ hall, const float* __restrict__ fcow,
    const float* __restrict__ fcob, const float* __restrict__ smw,
    const float* __restrict__ smb, float* __restrict__ out) {
  __shared__ __align__(16) float h_lds[16][260];
  __shared__ __align__(16) float fco[16][132];
  __shared__ float lg[16][6];
  const int tid = threadIdx.x;
  const int m0 = blockIdx.x * 16;
  {
    const float* src = hall + (size_t)m0 * DH_;
    for (int e = tid; e < 1024; e += 256) {
      float4 v = reinterpret_cast<const float4*>(src)[e];
      const int r = e >> 6, k = (e & 63) * 4;
      *reinterpret_cast<float4*>(&h_lds[r][k]) = v;
    }
  }
  __syncthreads();
  {
    const int f = tid & 127, half = tid >> 7;
    float acc[8];
    const float fb = fcob[f];
#pragma unroll
    for (int r = 0; r < 8; r++) acc[r] = fb;
    const float* wrow = fcow + (size_t)f * DH_;
    for (int k = 0; k < DH_; k += 4) {
      float4 w4 = *reinterpret_cast<const float4*>(wrow + k);
#pragma unroll
      for (int r = 0; r < 8; r++)
        acc[r] += dot4(w4, *reinterpret_cast<const float4*>(&h_lds[half * 8 + r][k]));
    }
#pragma unroll
    for (int r = 0; r < 8; r++) fco[half * 8 + r][f] = tanhf(acc[r]);
  }
  __syncthreads();
  if (tid < 96) {
    const int r = tid / 6, cc = tid % 6;
    float a = smb[cc];
    const float* sw = smw + cc * 128;
#pragma unroll 4
    for (int k = 0; k < 128; k++) a += sw[k] * fco[r][k];
    lg[r][cc] = a;
  }
  __syncthreads();
  if (tid < 16) {
    const int m = m0 + tid;
    const int t = m >> 8, b = m & 255;
    float mx = lg[tid][0];
#pragma unroll
    for (int cc = 1; cc < 6; cc++) mx = fmaxf(mx, lg[tid][cc]);
    float ssum = 0.f;
#pragma unroll
    for (int cc = 0; cc < 6; cc++) ssum += __expf(lg[tid][cc] - mx);
    float lse = mx + logf(ssum);
#pragma unroll
    for (int cc = 0; cc < 6; cc++)
      out[((size_t)b * T_ + t) * 6 + cc] = lg[tid][cc] - lse;
  }
}

// ---------------------------------------------------------------------------
extern "C" void kernel_launch(void* const* d_in, const int* in_sizes, int n_in,
                              void* d_out, int out_size, void* d_ws, size_t ws_size,
                              hipStream_t stream) {
  const float* mod0  = (const float*)d_in[0];
  const float* mod1  = (const float*)d_in[1];
  const float* mod2  = (const float*)d_in[2];
  const float* umask = (const float*)d_in[3];
  const float* w_ih0 = (const float*)d_in[4];
  const float* w_hh0 = (const float*)d_in[5];
  const float* b_ih0 = (const float*)d_in[6];
  const float* b_hh0 = (const float*)d_in[7];
  const float* fc_w0 = (const float*)d_in[8];
  const float* fc_b0 = (const float*)d_in[9];
  const float* w_ih1 = (const float*)d_in[10];
  const float* w_hh1 = (const float*)d_in[11];
  const float* b_ih1 = (const float*)d_in[12];
  const float* b_hh1 = (const float*)d_in[13];
  const float* fc_w1 = (const float*)d_in[14];
  const float* fc_b1 = (const float*)d_in[15];
  const float* w_ih2 = (const float*)d_in[16];
  const float* w_hh2 = (const float*)d_in[17];
  const float* b_ih2 = (const float*)d_in[18];
  const float* b_hh2 = (const float*)d_in[19];
  const float* fc_w2 = (const float*)d_in[20];
  const float* fc_b2 = (const float*)d_in[21];
  const float* w_ih_d = (const float*)d_in[22];
  const float* w_hh_d = (const float*)d_in[23];
  const float* b_ih_d = (const float*)d_in[24];
  const float* b_hh_d = (const float*)d_in[25];
  const float* fco_w  = (const float*)d_in[26];
  const float* fco_b  = (const float*)d_in[27];
  const float* sm_w   = (const float*)d_in[28];
  const float* sm_b   = (const float*)d_in[29];

  // workspace layout (floats), ~202 MB total (<= round-1 footprint):
  //   [0, M*1280)  : gx0|gx1|gx2  -> later reused as gxd [0,M*1024) + hall [M*1024,M*1280)
  float* ws    = (float*)d_ws;
  float* gx0   = ws;                                  // M*512
  float* gx1   = gx0 + (size_t)M_ * 512;              // M*256
  float* gx2   = gx1 + (size_t)M_ * 256;              // M*512
  float* gxd   = ws;                                  // M*1024 (reuse, gx* dead)
  float* hall  = ws + (size_t)M_ * 1024;              // M*256 (reuse gx2 tail)
  float* dfeat = ws + (size_t)M_ * 1280;              // M*256 (stride 256, pad zeroed)
  float* biasd = dfeat + (size_t)M_ * 256;            // 1024
  float* bias0 = biasd + 1024;                        // 512
  float* bias1 = bias0 + 512;                         // 256
  float* bias2 = bias1 + 256;                         // 512
  float* wihd  = bias2 + 512;                         // 1024*256 padded w_ih_d
  int*   bar   = (int*)(wihd + 1024 * 256);           // 512 ints (16 groups x 128B)

  prep_kernel<<<64, 256, 0, stream>>>(w_ih_d, b_ih_d, b_hh_d,
      b_ih0, b_hh0, b_ih1, b_hh1, b_ih2, b_hh2,
      wihd, dfeat, biasd, bias0, bias1, bias2, bar);

  proj_gemm<true><<<dim3(8,  M_ / 64), 256, 0, stream>>>(mod0, w_ih0, bias0, umask, gx0, 300, 512);
  proj_gemm<true><<<dim3(4,  M_ / 64), 256, 0, stream>>>(mod1, w_ih1, bias1, umask, gx1, 100, 256);
  proj_gemm<true><<<dim3(8,  M_ / 64), 256, 0, stream>>>(mod2, w_ih2, bias2, umask, gx2, 512, 512);

  ModParams p;
  p.gx0 = gx0; p.gx1 = gx1; p.gx2 = gx2;
  p.whh0 = w_hh0; p.whh1 = w_hh1; p.whh2 = w_hh2;
  p.fcw0 = fc_w0; p.fcw1 = fc_w1; p.fcw2 = fc_w2;
  p.fcb0 = fc_b0; p.fcb1 = fc_b1; p.fcb2 = fc_b2;
  mod_lstm<<<192, 256, 0, stream>>>(p, umask, dfeat);

  // dialogue input projection: gxd = dfeat @ wihd^T + biasd (overwrites gx*)
  proj_gemm<false><<<dim3(16, M_ / 64), 256, 0, stream>>>(dfeat, wihd, biasd, nullptr, gxd, 256, 1024);

  hipFuncSetAttribute(reinterpret_cast<const void*>(dlg_recur),
                      hipFuncAttributeMaxDynamicSharedMemorySize, DLG_LDS_BYTES);
  dlg_recur<<<256, 256, DLG_LDS_BYTES, stream>>>(gxd, w_hh_d, hall, bar);

  out_head<<<M_ / 16, 256, 0, stream>>>(hall, fco_w, fco_b, sm_w, sm_b, (float*)d_out);
}